// Round 3
// baseline (959.245 us; speedup 1.0000x reference)
//
#include <hip/hip_runtime.h>
#include <hip/hip_bf16.h>
#include <stdint.h>

#define NB 32
#define NT 2048
#define ND 1024   // DQ == DV == shared K dim
#define NU 1024

typedef __attribute__((ext_vector_type(8))) short bf16x8;
typedef __attribute__((ext_vector_type(4))) float f32x4;
typedef __attribute__((ext_vector_type(4))) unsigned short us4;
typedef __attribute__((ext_vector_type(8))) unsigned short us8;

__device__ __forceinline__ unsigned short f2bf(float f) {
  unsigned int u = __float_as_uint(f);
  u = (u + 0x7fffu + ((u >> 16) & 1u)) >> 16;   // round-to-nearest-even
  return (unsigned short)u;
}

__device__ __forceinline__ float bf2f(unsigned short h) {
  return __uint_as_float(((unsigned int)h) << 16);
}

__device__ __forceinline__ float tanh_fast(float x) {
  x = fminf(10.0f, fmaxf(-10.0f, x));
  float t = __expf(2.0f * x);
  return 1.0f - 2.0f * __builtin_amdgcn_rcpf(t + 1.0f);
}

__device__ __forceinline__ void gload_lds16(const void* g, void* s) {
  __builtin_amdgcn_global_load_lds(
      (const __attribute__((address_space(1))) unsigned int*)g,
      (__attribute__((address_space(3))) unsigned int*)s, 16, 0, 0);
}

// ---------------- fused prep: qb [0,256) | wst [256,1280) | cvt [1280,34048) -
// qb blocks first: they're the per-block latency long-pole; they hide inside
// the cvt bandwidth pass.
__global__ void prep_kernel(const float* __restrict__ values,
                            const float* __restrict__ Ws,
                            const float* __restrict__ query,
                            const float* __restrict__ Wh,
                            const float* __restrict__ bh,
                            const float* __restrict__ bs,
                            const float* __restrict__ bc,
                            unsigned short* __restrict__ vbf,
                            unsigned short* __restrict__ Wst,
                            float* __restrict__ qb) {
  int bid = blockIdx.x;
  int tid = threadIdx.x;
  if (bid < 256) {
    // ---- qb[b][u] = query@Wh + bh + bs + bc ; block = (uc, b)
    int uc = bid & 7, b = bid >> 3;
    int ud = tid & 31, ds = tid >> 5;
    const float* q = query + (size_t)b * ND + ds * 128;
    const float4* W4 = (const float4*)Wh + (size_t)ds * 128 * 256 + uc * 32 + ud;
    float4 a = {0.f, 0.f, 0.f, 0.f};
#pragma unroll 4
    for (int d = 0; d < 128; ++d) {
      float qv = q[d];
      float4 w = W4[(size_t)d * 256];
      a.x = fmaf(qv, w.x, a.x);
      a.y = fmaf(qv, w.y, a.y);
      a.z = fmaf(qv, w.z, a.z);
      a.w = fmaf(qv, w.w, a.w);
    }
    __shared__ float4 red[8][32];
    red[ds][ud] = a;
    __syncthreads();
    if (tid < 32) {
      float4 s = red[0][tid];
#pragma unroll
      for (int r = 1; r < 8; ++r) {
        float4 t = red[r][tid];
        s.x += t.x; s.y += t.y; s.z += t.z; s.w += t.w;
      }
      int u = uc * 128 + tid * 4;
      s.x += bh[u + 0] + bs[u + 0] + bc[u + 0];
      s.y += bh[u + 1] + bs[u + 1] + bc[u + 1];
      s.z += bh[u + 2] + bs[u + 2] + bc[u + 2];
      s.w += bh[u + 3] + bs[u + 3] + bc[u + 3];
      ((float4*)(qb + (size_t)b * NU))[uc * 32 + tid] = s;
    }
  } else if (bid < 1280) {
    // ---- Ws [d][u] -> Wst [u][d] bf16
    int b2 = bid - 256;
    int d0 = (b2 & 31) * 32, u0 = (b2 >> 5) * 32;
    __shared__ float tile[32][33];
    int c = tid & 31, r8 = tid >> 5;
#pragma unroll
    for (int i = 0; i < 4; ++i) {
      int rr = i * 8 + r8;
      tile[rr][c] = Ws[(size_t)(d0 + rr) * NU + u0 + c];
    }
    __syncthreads();
#pragma unroll
    for (int i = 0; i < 4; ++i) {
      int rr = i * 8 + r8;
      Wst[(size_t)(u0 + rr) * ND + d0 + c] = f2bf(tile[c][rr]);
    }
  } else {
    // ---- values fp32 -> bf16
    size_t idx = ((size_t)(bid - 1280) * 256 + tid) * 8;
    const float4* p = (const float4*)(values + idx);
    float4 x = p[0], y = p[1];
    us8 h;
    h[0] = f2bf(x.x); h[1] = f2bf(x.y); h[2] = f2bf(x.z); h[3] = f2bf(x.w);
    h[4] = f2bf(y.x); h[5] = f2bf(y.y); h[6] = f2bf(y.z); h[7] = f2bf(y.w);
    *(us8*)(vbf + idx) = h;
  }
}

// ---------------- main fused GEMM + tanh + Vw-dot + exp/stats ---------------
__launch_bounds__(256)
__global__ void score_gemm_bf16(const unsigned short* __restrict__ vbf,
                                const unsigned short* __restrict__ Wst,
                                const float* __restrict__ qb,
                                const float* __restrict__ cov,
                                const float* __restrict__ Wc,
                                const float* __restrict__ Vw,
                                float* __restrict__ scores,
                                float* __restrict__ expsc,
                                float* __restrict__ stats,
                                int* __restrict__ cnt) {
  // bid -> (g = (tc,b) group, uc) with all 8 uc of a group on one XCD
  int bid = blockIdx.x;
  int g  = ((bid >> 6) << 3) | (bid & 7);
  int uc = (bid >> 3) & 7;
  int tc = g & 15;
  int b  = g >> 4;
  const int t0 = tc * 128, u0 = uc * 128;
  const int tid = threadIdx.x;

  __shared__ unsigned short As[128 * 32];   // [row][k], chunk-swizzled
  __shared__ unsigned short Bs[128 * 32];
  __shared__ float covs[128], qbs[128], wcs[128], vws[128];
  __shared__ int winner;
  __shared__ float sred[2];

  if (tid < 128) {
    covs[tid] = cov[(size_t)b * NT + t0 + tid];
    qbs[tid]  = qb[(size_t)b * NU + u0 + tid];
    wcs[tid]  = Wc[u0 + tid];
    vws[tid]  = Vw[u0 + tid];
  }

  f32x4 acc[4][4];
#pragma unroll
  for (int i = 0; i < 4; ++i)
#pragma unroll
    for (int j = 0; j < 4; ++j)
      acc[i][j] = (f32x4){0.f, 0.f, 0.f, 0.f};

  const int lane = tid & 63;
  const int wave = tid >> 6;
  const int wm = wave >> 1, wn = wave & 1;
  const int q = lane >> 4, ln = lane & 15;

  const int Lr = lane >> 2;
  const int cswz = (lane & 3) ^ ((Lr >> 1) & 3);
  const unsigned short* pA0 = vbf + (size_t)(b * NT + t0 + wave * 32 + Lr) * ND + cswz * 8;
  const unsigned short* pA1 = pA0 + (size_t)16 * ND;
  const unsigned short* pB0 = Wst + (size_t)(u0 + wave * 32 + Lr) * ND + cswz * 8;
  const unsigned short* pB1 = pB0 + (size_t)16 * ND;
  unsigned short* sA0 = &As[(wave * 32) * 32];
  unsigned short* sA1 = &As[(wave * 32 + 16) * 32];
  unsigned short* sB0 = &Bs[(wave * 32) * 32];
  unsigned short* sB1 = &Bs[(wave * 32 + 16) * 32];

  const int swz8 = (q ^ ((ln >> 1) & 3)) * 8;
  const unsigned short* aP = &As[(wm * 64 + ln) * 32 + swz8];
  const unsigned short* bP = &Bs[(wn * 64 + ln) * 32 + swz8];

  for (int kk = 0; kk < ND; kk += 32) {
    gload_lds16(pA0, sA0);
    gload_lds16(pA1, sA1);
    gload_lds16(pB0, sB0);
    gload_lds16(pB1, sB1);
    pA0 += 32; pA1 += 32; pB0 += 32; pB1 += 32;
    __syncthreads();

    bf16x8 a[4], bb[4];
#pragma unroll
    for (int i = 0; i < 4; ++i) {
      a[i]  = *(const bf16x8*)(aP + i * 16 * 32);
      bb[i] = *(const bf16x8*)(bP + i * 16 * 32);
    }
#pragma unroll
    for (int i = 0; i < 4; ++i)
#pragma unroll
      for (int j = 0; j < 4; ++j)
        acc[i][j] = __builtin_amdgcn_mfma_f32_16x16x32_bf16(a[i], bb[j], acc[i][j], 0, 0, 0);
    __syncthreads();
  }

  // epilogue: pre = acc + qb[u] + cov[t]*Wc[u]; partial += Vw[u]*tanh(pre)
  float part[4][4];
#pragma unroll
  for (int tm = 0; tm < 4; ++tm)
#pragma unroll
    for (int r = 0; r < 4; ++r) part[tm][r] = 0.f;

#pragma unroll
  for (int tn = 0; tn < 4; ++tn) {
    int n = wn * 64 + tn * 16 + ln;
    float qv = qbs[n], wc = wcs[n], vw = vws[n];
#pragma unroll
    for (int tm = 0; tm < 4; ++tm) {
#pragma unroll
      for (int r = 0; r < 4; ++r) {
        int m = wm * 64 + tm * 16 + q * 4 + r;
        float pre = acc[tm][tn][r] + qv + covs[m] * wc;
        part[tm][r] += vw * tanh_fast(pre);
      }
    }
  }
#pragma unroll
  for (int tm = 0; tm < 4; ++tm) {
#pragma unroll
    for (int r = 0; r < 4; ++r) {
      float v = part[tm][r];
      v += __shfl_xor(v, 1);
      v += __shfl_xor(v, 2);
      v += __shfl_xor(v, 4);
      v += __shfl_xor(v, 8);
      if (ln == 0) {
        int m = wm * 64 + tm * 16 + q * 4 + r;
        atomicAdd(&scores[(size_t)b * NT + t0 + m], v);
      }
    }
  }

  // ---- softmax stats fused via per-(b,tc) completion counter.
  // |score| <= sum|Vw| ~= 26, so exp without max-subtraction is safe.
  __threadfence();
  __syncthreads();
  if (tid == 0) {
    int old = __hip_atomic_fetch_add(&cnt[b * 16 + tc], 1,
                                     __ATOMIC_ACQ_REL, __HIP_MEMORY_SCOPE_AGENT);
    winner = (old == 7) ? 1 : 0;
  }
  __syncthreads();
  if (winner) {
    __threadfence();
    if (tid < 128) {   // waves 0,1 fully active
      float s = __hip_atomic_load(&scores[(size_t)b * NT + t0 + tid],
                                  __ATOMIC_ACQUIRE, __HIP_MEMORY_SCOPE_AGENT);
      float e = __expf(s);
      expsc[(size_t)b * NT + t0 + tid] = e;
#pragma unroll
      for (int off = 1; off < 64; off <<= 1) e += __shfl_xor(e, off);
      if (lane == 0) sred[tid >> 6] = e;
    }
    __syncthreads();
    if (tid == 0) atomicAdd(&stats[b], sred[0] + sred[1]);
  }
}

// ---------------- fused weights + coverage + context (bf16 values) ----------
__global__ void context_fused(const unsigned short* __restrict__ vbf,
                              const float* __restrict__ expsc,
                              const float* __restrict__ stats,
                              const float* __restrict__ cov,
                              float* __restrict__ out) {
  int tc = blockIdx.x;           // 16 chunks of 128 t
  int b  = blockIdx.y;
  int tid = threadIdx.x;
  __shared__ float wsm[128];
  float rinv = 1.0f / stats[b];
  int t0 = tc * 128;
  size_t sbase = (size_t)b * NT + t0;
  if (tid < 128) {
    float w = expsc[sbase + tid] * rinv;
    wsm[tid] = w;
    out[32768 + sbase + tid] = w;                    // attention_weights
    out[98304 + sbase + tid] = w + cov[sbase + tid]; // coverage
  }
  __syncthreads();
  const unsigned short* vb = vbf + (size_t)(b * NT + t0) * ND + tid * 4;
  float a0 = 0.f, a1 = 0.f, a2 = 0.f, a3 = 0.f;
#pragma unroll 4
  for (int t = 0; t < 128; ++t) {
    float wt = wsm[t];
    us4 h = *(const us4*)(vb + (size_t)t * ND);
    a0 = fmaf(wt, bf2f(h.x), a0);
    a1 = fmaf(wt, bf2f(h.y), a1);
    a2 = fmaf(wt, bf2f(h.z), a2);
    a3 = fmaf(wt, bf2f(h.w), a3);
  }
  float* c = out + (size_t)b * ND + tid * 4;
  atomicAdd(c + 0, a0);
  atomicAdd(c + 1, a1);
  atomicAdd(c + 2, a2);
  atomicAdd(c + 3, a3);
}

// =================== fallback path (small ws) ================================
__global__ void wst_kernel(const float* __restrict__ Ws,
                           unsigned short* __restrict__ Wst) {
  __shared__ float tile[32][33];
  int d0 = blockIdx.x * 32, u0 = blockIdx.y * 32;
  int c = threadIdx.x & 31, r8 = threadIdx.x >> 5;
#pragma unroll
  for (int i = 0; i < 4; ++i) {
    int rr = i * 8 + r8;
    tile[rr][c] = Ws[(size_t)(d0 + rr) * NU + u0 + c];
  }
  __syncthreads();
#pragma unroll
  for (int i = 0; i < 4; ++i) {
    int rr = i * 8 + r8;
    Wst[(size_t)(u0 + rr) * ND + d0 + c] = f2bf(tile[c][rr]);
  }
}

__global__ void qb_kernel2(const float* __restrict__ query,
                           const float* __restrict__ Wh,
                           const float* __restrict__ bh,
                           const float* __restrict__ bs,
                           const float* __restrict__ bc,
                           float* __restrict__ qb) {
  int uc = blockIdx.x, b = blockIdx.y;
  int tid = threadIdx.x, ud = tid & 31, ds = tid >> 5;
  const float* q = query + (size_t)b * ND + ds * 128;
  const float4* W4 = (const float4*)Wh + (size_t)ds * 128 * 256 + uc * 32 + ud;
  float4 a = {0.f, 0.f, 0.f, 0.f};
  for (int d = 0; d < 128; ++d) {
    float qv = q[d];
    float4 w = W4[(size_t)d * 256];
    a.x = fmaf(qv, w.x, a.x);
    a.y = fmaf(qv, w.y, a.y);
    a.z = fmaf(qv, w.z, a.z);
    a.w = fmaf(qv, w.w, a.w);
  }
  __shared__ float4 red[8][32];
  red[ds][ud] = a;
  __syncthreads();
  if (tid < 32) {
    float4 s = red[0][tid];
#pragma unroll
    for (int r = 1; r < 8; ++r) {
      float4 t = red[r][tid];
      s.x += t.x; s.y += t.y; s.z += t.z; s.w += t.w;
    }
    int u = uc * 128 + tid * 4;
    s.x += bh[u + 0] + bs[u + 0] + bc[u + 0];
    s.y += bh[u + 1] + bs[u + 1] + bc[u + 1];
    s.z += bh[u + 2] + bs[u + 2] + bc[u + 2];
    s.w += bh[u + 3] + bs[u + 3] + bc[u + 3];
    ((float4*)(qb + (size_t)b * NU))[uc * 32 + tid] = s;
  }
}

__launch_bounds__(256)
__global__ void score_gemm_f32(const float* __restrict__ values,
                               const unsigned short* __restrict__ Wst,
                               const float* __restrict__ qb,
                               const float* __restrict__ cov,
                               const float* __restrict__ Wc,
                               const float* __restrict__ Vw,
                               float* __restrict__ scores) {
  const int uc = blockIdx.x, tc = blockIdx.y, b = blockIdx.z;
  const int t0 = tc * 128, u0 = uc * 128;
  const int tid = threadIdx.x;
  __shared__ unsigned short As[128 * 40];
  __shared__ unsigned short Bs[128 * 40];
  __shared__ float covs[128], qbs[128], wcs[128], vws[128];
  if (tid < 128) {
    covs[tid] = cov[(size_t)b * NT + t0 + tid];
    qbs[tid]  = qb[(size_t)b * NU + u0 + tid];
    wcs[tid]  = Wc[u0 + tid];
    vws[tid]  = Vw[u0 + tid];
  }
  f32x4 acc[4][4];
#pragma unroll
  for (int i = 0; i < 4; ++i)
#pragma unroll
    for (int j = 0; j < 4; ++j) acc[i][j] = (f32x4){0.f, 0.f, 0.f, 0.f};
  const int lane = tid & 63, wave = tid >> 6;
  const int wm = wave >> 1, wn = wave & 1;
  const int q = lane >> 4, ln = lane & 15;
  const int ar = tid >> 3, ac = (tid & 7) * 4;
  const int brow = tid >> 2, bcol = (tid & 3) * 8;
  const float* Abase = values + (size_t)(b * NT + t0) * ND;
  const unsigned short* Bbase = Wst + (size_t)u0 * ND;
  for (int kk = 0; kk < ND; kk += 32) {
#pragma unroll
    for (int p = 0; p < 4; ++p) {
      int row = p * 32 + ar;
      float4 v = *(const float4*)(Abase + (size_t)row * ND + kk + ac);
      us4 h;
      h.x = f2bf(v.x); h.y = f2bf(v.y); h.z = f2bf(v.z); h.w = f2bf(v.w);
      *(us4*)&As[row * 40 + ac] = h;
    }
#pragma unroll
    for (int p = 0; p < 2; ++p) {
      int row = p * 64 + brow;
      uint4 v = *(const uint4*)(Bbase + (size_t)row * ND + kk + bcol);
      *(uint4*)&Bs[row * 40 + bcol] = v;
    }
    __syncthreads();
    bf16x8 a[4], bb[4];
#pragma unroll
    for (int i = 0; i < 4; ++i) {
      a[i]  = *(const bf16x8*)&As[(wm * 64 + i * 16 + ln) * 40 + q * 8];
      bb[i] = *(const bf16x8*)&Bs[(wn * 64 + i * 16 + ln) * 40 + q * 8];
    }
#pragma unroll
    for (int i = 0; i < 4; ++i)
#pragma unroll
      for (int j = 0; j < 4; ++j)
        acc[i][j] = __builtin_amdgcn_mfma_f32_16x16x32_bf16(a[i], bb[j], acc[i][j], 0, 0, 0);
    __syncthreads();
  }
  float part[4][4];
#pragma unroll
  for (int tm = 0; tm < 4; ++tm)
#pragma unroll
    for (int r = 0; r < 4; ++r) part[tm][r] = 0.f;
#pragma unroll
  for (int tn = 0; tn < 4; ++tn) {
    int n = wn * 64 + tn * 16 + ln;
    float qv = qbs[n], wc = wcs[n], vw = vws[n];
#pragma unroll
    for (int tm = 0; tm < 4; ++tm) {
#pragma unroll
      for (int r = 0; r < 4; ++r) {
        int m = wm * 64 + tm * 16 + q * 4 + r;
        float pre = acc[tm][tn][r] + qv + covs[m] * wc;
        part[tm][r] += vw * tanh_fast(pre);
      }
    }
  }
#pragma unroll
  for (int tm = 0; tm < 4; ++tm) {
#pragma unroll
    for (int r = 0; r < 4; ++r) {
      float v = part[tm][r];
      v += __shfl_xor(v, 1);
      v += __shfl_xor(v, 2);
      v += __shfl_xor(v, 4);
      v += __shfl_xor(v, 8);
      if (ln == 0) {
        int m = wm * 64 + tm * 16 + q * 4 + r;
        atomicAdd(&scores[(size_t)b * NT + t0 + m], v);
      }
    }
  }
}

__global__ void softmax_fused(const float* __restrict__ scores,
                              const float* __restrict__ cov,
                              float* __restrict__ out) {
  int b = blockIdx.x, tid = threadIdx.x;
  __shared__ float red[4], red2[4];
  const float* s = scores + (size_t)b * NT;
  float m = -1e30f;
  for (int t = tid; t < NT; t += 256) m = fmaxf(m, s[t]);
#pragma unroll
  for (int off = 1; off < 64; off <<= 1) m = fmaxf(m, __shfl_xor(m, off));
  if ((tid & 63) == 0) red[tid >> 6] = m;
  __syncthreads();
  m = fmaxf(fmaxf(red[0], red[1]), fmaxf(red[2], red[3]));
  float l = 0.f;
  for (int t = tid; t < NT; t += 256) l += __expf(s[t] - m);
#pragma unroll
  for (int off = 1; off < 64; off <<= 1) l += __shfl_xor(l, off);
  if ((tid & 63) == 0) red2[tid >> 6] = l;
  __syncthreads();
  float rl = 1.0f / (red2[0] + red2[1] + red2[2] + red2[3]);
  for (int t = tid; t < NT; t += 256) {
    float w = __expf(s[t] - m) * rl;
    size_t idx = (size_t)b * NT + t;
    out[32768 + idx] = w;
    out[98304 + idx] = w + cov[idx];
  }
}

__global__ void context_kernel(const float* __restrict__ values,
                               const float* __restrict__ attn,
                               float* __restrict__ ctx) {
  int b = blockIdx.y, t0 = blockIdx.x * 128, tid = threadIdx.x;
  const float4* v4 = (const float4*)(values + (size_t)b * NT * ND);
  const float* w = attn + (size_t)b * NT + t0;
  float ax = 0.f, ay = 0.f, az = 0.f, aw = 0.f;
  for (int t = 0; t < 128; ++t) {
    float wt = w[t];
    float4 x = v4[(size_t)(t0 + t) * 256 + tid];
    ax = fmaf(wt, x.x, ax);
    ay = fmaf(wt, x.y, ay);
    az = fmaf(wt, x.z, az);
    aw = fmaf(wt, x.w, aw);
  }
  float* c = ctx + (size_t)b * ND + tid * 4;
  atomicAdd(c + 0, ax);
  atomicAdd(c + 1, ay);
  atomicAdd(c + 2, az);
  atomicAdd(c + 3, aw);
}

extern "C" void kernel_launch(void* const* d_in, const int* in_sizes, int n_in,
                              void* d_out, int out_size, void* d_ws, size_t ws_size,
                              hipStream_t stream) {
  (void)in_sizes; (void)n_in; (void)out_size;
  const float* query  = (const float*)d_in[0];
  const float* values = (const float*)d_in[1];
  const float* cov    = (const float*)d_in[2];
  const float* Wh     = (const float*)d_in[3];
  const float* bh     = (const float*)d_in[4];
  const float* Ws     = (const float*)d_in[5];
  const float* bs     = (const float*)d_in[6];
  const float* Wc     = (const float*)d_in[7];
  const float* bc     = (const float*)d_in[8];
  const float* Vw     = (const float*)d_in[9];
  // d_in[10] = Vb: softmax-invariant, unused.

  float* out = (float*)d_out;   // [0,32768)=ctx, [32768,98304)=attn, [98304,163840)=cov
  char* ws = (char*)d_ws;

  const size_t VBF = (size_t)NB * NT * ND * 2;                 // 128 MB
  const size_t O_WST   = VBF;
  const size_t O_QB    = O_WST + 2u * 1024 * 1024;
  const size_t O_SC    = O_QB + 128u * 1024;
  const size_t O_EXP   = O_SC + 256u * 1024;
  const size_t O_STATS = O_EXP + 256u * 1024;
  const size_t O_CNT   = O_STATS + 256;
  const size_t need    = O_CNT + 2048;

  if (ws_size >= need) {
    unsigned short* vbf = (unsigned short*)ws;
    unsigned short* Wst = (unsigned short*)(ws + O_WST);
    float* qb     = (float*)(ws + O_QB);
    float* scores = (float*)(ws + O_SC);
    float* expsc  = (float*)(ws + O_EXP);
    float* stats  = (float*)(ws + O_STATS);
    int*   cnt    = (int*)(ws + O_CNT);

    // zero scores+expsc+stats+cnt in one shot, ctx region of out in another
    hipMemsetAsync(scores, 0, need - O_SC, stream);
    hipMemsetAsync(out, 0, (size_t)NB * ND * sizeof(float), stream);

    prep_kernel<<<34048, 256, 0, stream>>>(values, Ws, query, Wh, bh, bs, bc,
                                           vbf, Wst, qb);
    score_gemm_bf16<<<4096, 256, 0, stream>>>(vbf, Wst, qb, cov, Wc, Vw,
                                              scores, expsc, stats, cnt);
    context_fused<<<dim3(16, 32), 256, 0, stream>>>(vbf, expsc, stats, cov, out);
  } else {
    unsigned short* Wst = (unsigned short*)ws;
    float* qb     = (float*)(ws + 2u * 1024 * 1024);
    float* scores = (float*)(ws + 2u * 1024 * 1024 + 128u * 1024);

    hipMemsetAsync(scores, 0, (size_t)NB * NT * sizeof(float), stream);
    hipMemsetAsync(out, 0, (size_t)NB * ND * sizeof(float), stream);

    wst_kernel<<<dim3(32, 32), 256, 0, stream>>>(Ws, Wst);
    qb_kernel2<<<dim3(8, 32), 256, 0, stream>>>(query, Wh, bh, bs, bc, qb);
    score_gemm_f32<<<dim3(8, 16, 32), 256, 0, stream>>>(values, Wst, qb, cov, Wc, Vw, scores);
    softmax_fused<<<NB, 256, 0, stream>>>(scores, cov, out);
    context_kernel<<<dim3(16, 32), 256, 0, stream>>>(values, out + 32768, out);
  }
}

// Round 4
// 595.288 us; speedup vs baseline: 1.6114x; 1.6114x over previous
//
#include <hip/hip_runtime.h>
#include <hip/hip_bf16.h>
#include <stdint.h>

#define NB 32
#define NT 2048
#define ND 1024   // DQ == DV == shared K dim
#define NU 1024

typedef __attribute__((ext_vector_type(8))) short bf16x8;
typedef __attribute__((ext_vector_type(4))) float f32x4;
typedef __attribute__((ext_vector_type(4))) unsigned short us4;
typedef __attribute__((ext_vector_type(8))) unsigned short us8;

__device__ __forceinline__ unsigned short f2bf(float f) {
  unsigned int u = __float_as_uint(f);
  u = (u + 0x7fffu + ((u >> 16) & 1u)) >> 16;   // round-to-nearest-even
  return (unsigned short)u;
}

__device__ __forceinline__ float bf2f(unsigned short h) {
  return __uint_as_float(((unsigned int)h) << 16);
}

__device__ __forceinline__ float tanh_fast(float x) {
  x = fminf(10.0f, fmaxf(-10.0f, x));
  float t = __expf(2.0f * x);
  return 1.0f - 2.0f * __builtin_amdgcn_rcpf(t + 1.0f);
}

__device__ __forceinline__ void gload_lds16(const void* g, void* s) {
  __builtin_amdgcn_global_load_lds(
      (const __attribute__((address_space(1))) unsigned int*)g,
      (__attribute__((address_space(3))) unsigned int*)s, 16, 0, 0);
}

// ---------------- fused prep: qb [0,256) | wst [256,1280) | cvt [1280,34048) -
// qb blocks first: they're the per-block latency long-pole; they hide inside
// the cvt bandwidth pass. NO device-scope fences anywhere (round-3 lesson:
// per-block __threadfence/agent-scope atomics tripled the gemm time).
__global__ void prep_kernel(const float* __restrict__ values,
                            const float* __restrict__ Ws,
                            const float* __restrict__ query,
                            const float* __restrict__ Wh,
                            const float* __restrict__ bh,
                            const float* __restrict__ bs,
                            const float* __restrict__ bc,
                            unsigned short* __restrict__ vbf,
                            unsigned short* __restrict__ Wst,
                            float* __restrict__ qb) {
  int bid = blockIdx.x;
  int tid = threadIdx.x;
  if (bid < 256) {
    // ---- qb[b][u] = query@Wh + bh + bs + bc ; block = (uc, b)
    int uc = bid & 7, b = bid >> 3;
    int ud = tid & 31, ds = tid >> 5;
    const float* q = query + (size_t)b * ND + ds * 128;
    const float4* W4 = (const float4*)Wh + (size_t)ds * 128 * 256 + uc * 32 + ud;
    float4 a = {0.f, 0.f, 0.f, 0.f};
#pragma unroll 4
    for (int d = 0; d < 128; ++d) {
      float qv = q[d];
      float4 w = W4[(size_t)d * 256];
      a.x = fmaf(qv, w.x, a.x);
      a.y = fmaf(qv, w.y, a.y);
      a.z = fmaf(qv, w.z, a.z);
      a.w = fmaf(qv, w.w, a.w);
    }
    __shared__ float4 red[8][32];
    red[ds][ud] = a;
    __syncthreads();
    if (tid < 32) {
      float4 s = red[0][tid];
#pragma unroll
      for (int r = 1; r < 8; ++r) {
        float4 t = red[r][tid];
        s.x += t.x; s.y += t.y; s.z += t.z; s.w += t.w;
      }
      int u = uc * 128 + tid * 4;
      s.x += bh[u + 0] + bs[u + 0] + bc[u + 0];
      s.y += bh[u + 1] + bs[u + 1] + bc[u + 1];
      s.z += bh[u + 2] + bs[u + 2] + bc[u + 2];
      s.w += bh[u + 3] + bs[u + 3] + bc[u + 3];
      ((float4*)(qb + (size_t)b * NU))[uc * 32 + tid] = s;
    }
  } else if (bid < 1280) {
    // ---- Ws [d][u] -> Wst [u][d] bf16
    int b2 = bid - 256;
    int d0 = (b2 & 31) * 32, u0 = (b2 >> 5) * 32;
    __shared__ float tile[32][33];
    int c = tid & 31, r8 = tid >> 5;
#pragma unroll
    for (int i = 0; i < 4; ++i) {
      int rr = i * 8 + r8;
      tile[rr][c] = Ws[(size_t)(d0 + rr) * NU + u0 + c];
    }
    __syncthreads();
#pragma unroll
    for (int i = 0; i < 4; ++i) {
      int rr = i * 8 + r8;
      Wst[(size_t)(u0 + rr) * ND + d0 + c] = f2bf(tile[c][rr]);
    }
  } else {
    // ---- values fp32 -> bf16
    size_t idx = ((size_t)(bid - 1280) * 256 + tid) * 8;
    const float4* p = (const float4*)(values + idx);
    float4 x = p[0], y = p[1];
    us8 h;
    h[0] = f2bf(x.x); h[1] = f2bf(x.y); h[2] = f2bf(x.z); h[3] = f2bf(x.w);
    h[4] = f2bf(y.x); h[5] = f2bf(y.y); h[6] = f2bf(y.z); h[7] = f2bf(y.w);
    *(us8*)(vbf + idx) = h;
  }
}

// ---------------- main fused GEMM + tanh + Vw-dot (round-2 body, 202 us) ----
__launch_bounds__(256)
__global__ void score_gemm_bf16(const unsigned short* __restrict__ vbf,
                                const unsigned short* __restrict__ Wst,
                                const float* __restrict__ qb,
                                const float* __restrict__ cov,
                                const float* __restrict__ Wc,
                                const float* __restrict__ Vw,
                                float* __restrict__ scores) {
  // bid -> (g = (tc,b) group, uc) with all 8 uc of a group on one XCD
  int bid = blockIdx.x;
  int g  = ((bid >> 6) << 3) | (bid & 7);
  int uc = (bid >> 3) & 7;
  int tc = g & 15;
  int b  = g >> 4;
  const int t0 = tc * 128, u0 = uc * 128;
  const int tid = threadIdx.x;

  __shared__ unsigned short As[128 * 32];   // [row][k], chunk-swizzled
  __shared__ unsigned short Bs[128 * 32];
  __shared__ float covs[128], qbs[128], wcs[128], vws[128];

  if (tid < 128) {
    covs[tid] = cov[(size_t)b * NT + t0 + tid];
    qbs[tid]  = qb[(size_t)b * NU + u0 + tid];
    wcs[tid]  = Wc[u0 + tid];
    vws[tid]  = Vw[u0 + tid];
  }

  f32x4 acc[4][4];
#pragma unroll
  for (int i = 0; i < 4; ++i)
#pragma unroll
    for (int j = 0; j < 4; ++j)
      acc[i][j] = (f32x4){0.f, 0.f, 0.f, 0.f};

  const int lane = tid & 63;
  const int wave = tid >> 6;
  const int wm = wave >> 1, wn = wave & 1;
  const int q = lane >> 4, ln = lane & 15;

  const int Lr = lane >> 2;
  const int cswz = (lane & 3) ^ ((Lr >> 1) & 3);
  const unsigned short* pA0 = vbf + (size_t)(b * NT + t0 + wave * 32 + Lr) * ND + cswz * 8;
  const unsigned short* pA1 = pA0 + (size_t)16 * ND;
  const unsigned short* pB0 = Wst + (size_t)(u0 + wave * 32 + Lr) * ND + cswz * 8;
  const unsigned short* pB1 = pB0 + (size_t)16 * ND;
  unsigned short* sA0 = &As[(wave * 32) * 32];
  unsigned short* sA1 = &As[(wave * 32 + 16) * 32];
  unsigned short* sB0 = &Bs[(wave * 32) * 32];
  unsigned short* sB1 = &Bs[(wave * 32 + 16) * 32];

  const int swz8 = (q ^ ((ln >> 1) & 3)) * 8;
  const unsigned short* aP = &As[(wm * 64 + ln) * 32 + swz8];
  const unsigned short* bP = &Bs[(wn * 64 + ln) * 32 + swz8];

  for (int kk = 0; kk < ND; kk += 32) {
    gload_lds16(pA0, sA0);
    gload_lds16(pA1, sA1);
    gload_lds16(pB0, sB0);
    gload_lds16(pB1, sB1);
    pA0 += 32; pA1 += 32; pB0 += 32; pB1 += 32;
    __syncthreads();

    bf16x8 a[4], bb[4];
#pragma unroll
    for (int i = 0; i < 4; ++i) {
      a[i]  = *(const bf16x8*)(aP + i * 16 * 32);
      bb[i] = *(const bf16x8*)(bP + i * 16 * 32);
    }
#pragma unroll
    for (int i = 0; i < 4; ++i)
#pragma unroll
      for (int j = 0; j < 4; ++j)
        acc[i][j] = __builtin_amdgcn_mfma_f32_16x16x32_bf16(a[i], bb[j], acc[i][j], 0, 0, 0);
    __syncthreads();
  }

  // epilogue: pre = acc + qb[u] + cov[t]*Wc[u]; partial += Vw[u]*tanh(pre)
  float part[4][4];
#pragma unroll
  for (int tm = 0; tm < 4; ++tm)
#pragma unroll
    for (int r = 0; r < 4; ++r) part[tm][r] = 0.f;

#pragma unroll
  for (int tn = 0; tn < 4; ++tn) {
    int n = wn * 64 + tn * 16 + ln;
    float qv = qbs[n], wc = wcs[n], vw = vws[n];
#pragma unroll
    for (int tm = 0; tm < 4; ++tm) {
#pragma unroll
      for (int r = 0; r < 4; ++r) {
        int m = wm * 64 + tm * 16 + q * 4 + r;
        float pre = acc[tm][tn][r] + qv + covs[m] * wc;
        part[tm][r] += vw * tanh_fast(pre);
      }
    }
  }
#pragma unroll
  for (int tm = 0; tm < 4; ++tm) {
#pragma unroll
    for (int r = 0; r < 4; ++r) {
      float v = part[tm][r];
      v += __shfl_xor(v, 1);
      v += __shfl_xor(v, 2);
      v += __shfl_xor(v, 4);
      v += __shfl_xor(v, 8);
      if (ln == 0) {
        int m = wm * 64 + tm * 16 + q * 4 + r;
        atomicAdd(&scores[(size_t)b * NT + t0 + m], v);
      }
    }
  }
}

// ---------------- fused softmax + weights + coverage ------------------------
__global__ void softmax_fused(const float* __restrict__ scores,
                              const float* __restrict__ cov,
                              float* __restrict__ out) {
  int b = blockIdx.x, tid = threadIdx.x;
  __shared__ float red[4], red2[4];
  const float* s = scores + (size_t)b * NT;
  float m = -1e30f;
  for (int t = tid; t < NT; t += 256) m = fmaxf(m, s[t]);
#pragma unroll
  for (int off = 1; off < 64; off <<= 1) m = fmaxf(m, __shfl_xor(m, off));
  if ((tid & 63) == 0) red[tid >> 6] = m;
  __syncthreads();
  m = fmaxf(fmaxf(red[0], red[1]), fmaxf(red[2], red[3]));
  float l = 0.f;
  for (int t = tid; t < NT; t += 256) l += __expf(s[t] - m);
#pragma unroll
  for (int off = 1; off < 64; off <<= 1) l += __shfl_xor(l, off);
  if ((tid & 63) == 0) red2[tid >> 6] = l;
  __syncthreads();
  float rl = 1.0f / (red2[0] + red2[1] + red2[2] + red2[3]);
  for (int t = tid; t < NT; t += 256) {
    float w = __expf(s[t] - m) * rl;
    size_t idx = (size_t)b * NT + t;
    out[32768 + idx] = w;                   // attention_weights [B,T]
    out[98304 + idx] = w + cov[idx];        // coverage [B,T,1]
  }
}

// ---------------- context = sum_t w * values (bf16 values) ------------------
__global__ void context_fused(const unsigned short* __restrict__ vbf,
                              const float* __restrict__ attn,
                              float* __restrict__ out) {
  int tc = blockIdx.x;           // 16 chunks of 128 t
  int b  = blockIdx.y;
  int tid = threadIdx.x;
  __shared__ float wsm[128];
  int t0 = tc * 128;
  size_t sbase = (size_t)b * NT + t0;
  if (tid < 128) wsm[tid] = attn[sbase + tid];
  __syncthreads();
  const unsigned short* vb = vbf + (size_t)(b * NT + t0) * ND + tid * 4;
  float a0 = 0.f, a1 = 0.f, a2 = 0.f, a3 = 0.f;
#pragma unroll 4
  for (int t = 0; t < 128; ++t) {
    float wt = wsm[t];
    us4 h = *(const us4*)(vb + (size_t)t * ND);
    a0 = fmaf(wt, bf2f(h.x), a0);
    a1 = fmaf(wt, bf2f(h.y), a1);
    a2 = fmaf(wt, bf2f(h.z), a2);
    a3 = fmaf(wt, bf2f(h.w), a3);
  }
  float* c = out + (size_t)b * ND + tid * 4;
  atomicAdd(c + 0, a0);
  atomicAdd(c + 1, a1);
  atomicAdd(c + 2, a2);
  atomicAdd(c + 3, a3);
}

// =================== fallback path (small ws) ================================
__global__ void wst_kernel(const float* __restrict__ Ws,
                           unsigned short* __restrict__ Wst) {
  __shared__ float tile[32][33];
  int d0 = blockIdx.x * 32, u0 = blockIdx.y * 32;
  int c = threadIdx.x & 31, r8 = threadIdx.x >> 5;
#pragma unroll
  for (int i = 0; i < 4; ++i) {
    int rr = i * 8 + r8;
    tile[rr][c] = Ws[(size_t)(d0 + rr) * NU + u0 + c];
  }
  __syncthreads();
#pragma unroll
  for (int i = 0; i < 4; ++i) {
    int rr = i * 8 + r8;
    Wst[(size_t)(u0 + rr) * ND + d0 + c] = f2bf(tile[c][rr]);
  }
}

__global__ void qb_kernel2(const float* __restrict__ query,
                           const float* __restrict__ Wh,
                           const float* __restrict__ bh,
                           const float* __restrict__ bs,
                           const float* __restrict__ bc,
                           float* __restrict__ qb) {
  int uc = blockIdx.x, b = blockIdx.y;
  int tid = threadIdx.x, ud = tid & 31, ds = tid >> 5;
  const float* q = query + (size_t)b * ND + ds * 128;
  const float4* W4 = (const float4*)Wh + (size_t)ds * 128 * 256 + uc * 32 + ud;
  float4 a = {0.f, 0.f, 0.f, 0.f};
  for (int d = 0; d < 128; ++d) {
    float qv = q[d];
    float4 w = W4[(size_t)d * 256];
    a.x = fmaf(qv, w.x, a.x);
    a.y = fmaf(qv, w.y, a.y);
    a.z = fmaf(qv, w.z, a.z);
    a.w = fmaf(qv, w.w, a.w);
  }
  __shared__ float4 red[8][32];
  red[ds][ud] = a;
  __syncthreads();
  if (tid < 32) {
    float4 s = red[0][tid];
#pragma unroll
    for (int r = 1; r < 8; ++r) {
      float4 t = red[r][tid];
      s.x += t.x; s.y += t.y; s.z += t.z; s.w += t.w;
    }
    int u = uc * 128 + tid * 4;
    s.x += bh[u + 0] + bs[u + 0] + bc[u + 0];
    s.y += bh[u + 1] + bs[u + 1] + bc[u + 1];
    s.z += bh[u + 2] + bs[u + 2] + bc[u + 2];
    s.w += bh[u + 3] + bs[u + 3] + bc[u + 3];
    ((float4*)(qb + (size_t)b * NU))[uc * 32 + tid] = s;
  }
}

__launch_bounds__(256)
__global__ void score_gemm_f32(const float* __restrict__ values,
                               const unsigned short* __restrict__ Wst,
                               const float* __restrict__ qb,
                               const float* __restrict__ cov,
                               const float* __restrict__ Wc,
                               const float* __restrict__ Vw,
                               float* __restrict__ scores) {
  const int uc = blockIdx.x, tc = blockIdx.y, b = blockIdx.z;
  const int t0 = tc * 128, u0 = uc * 128;
  const int tid = threadIdx.x;
  __shared__ unsigned short As[128 * 40];
  __shared__ unsigned short Bs[128 * 40];
  __shared__ float covs[128], qbs[128], wcs[128], vws[128];
  if (tid < 128) {
    covs[tid] = cov[(size_t)b * NT + t0 + tid];
    qbs[tid]  = qb[(size_t)b * NU + u0 + tid];
    wcs[tid]  = Wc[u0 + tid];
    vws[tid]  = Vw[u0 + tid];
  }
  f32x4 acc[4][4];
#pragma unroll
  for (int i = 0; i < 4; ++i)
#pragma unroll
    for (int j = 0; j < 4; ++j) acc[i][j] = (f32x4){0.f, 0.f, 0.f, 0.f};
  const int lane = tid & 63, wave = tid >> 6;
  const int wm = wave >> 1, wn = wave & 1;
  const int q = lane >> 4, ln = lane & 15;
  const int ar = tid >> 3, ac = (tid & 7) * 4;
  const int brow = tid >> 2, bcol = (tid & 3) * 8;
  const float* Abase = values + (size_t)(b * NT + t0) * ND;
  const unsigned short* Bbase = Wst + (size_t)u0 * ND;
  for (int kk = 0; kk < ND; kk += 32) {
#pragma unroll
    for (int p = 0; p < 4; ++p) {
      int row = p * 32 + ar;
      float4 v = *(const float4*)(Abase + (size_t)row * ND + kk + ac);
      us4 h;
      h.x = f2bf(v.x); h.y = f2bf(v.y); h.z = f2bf(v.z); h.w = f2bf(v.w);
      *(us4*)&As[row * 40 + ac] = h;
    }
#pragma unroll
    for (int p = 0; p < 2; ++p) {
      int row = p * 64 + brow;
      uint4 v = *(const uint4*)(Bbase + (size_t)row * ND + kk + bcol);
      *(uint4*)&Bs[row * 40 + bcol] = v;
    }
    __syncthreads();
    bf16x8 a[4], bb[4];
#pragma unroll
    for (int i = 0; i < 4; ++i) {
      a[i]  = *(const bf16x8*)&As[(wm * 64 + i * 16 + ln) * 40 + q * 8];
      bb[i] = *(const bf16x8*)&Bs[(wn * 64 + i * 16 + ln) * 40 + q * 8];
    }
#pragma unroll
    for (int i = 0; i < 4; ++i)
#pragma unroll
      for (int j = 0; j < 4; ++j)
        acc[i][j] = __builtin_amdgcn_mfma_f32_16x16x32_bf16(a[i], bb[j], acc[i][j], 0, 0, 0);
    __syncthreads();
  }
  float part[4][4];
#pragma unroll
  for (int tm = 0; tm < 4; ++tm)
#pragma unroll
    for (int r = 0; r < 4; ++r) part[tm][r] = 0.f;
#pragma unroll
  for (int tn = 0; tn < 4; ++tn) {
    int n = wn * 64 + tn * 16 + ln;
    float qv = qbs[n], wc = wcs[n], vw = vws[n];
#pragma unroll
    for (int tm = 0; tm < 4; ++tm) {
#pragma unroll
      for (int r = 0; r < 4; ++r) {
        int m = wm * 64 + tm * 16 + q * 4 + r;
        float pre = acc[tm][tn][r] + qv + covs[m] * wc;
        part[tm][r] += vw * tanh_fast(pre);
      }
    }
  }
#pragma unroll
  for (int tm = 0; tm < 4; ++tm) {
#pragma unroll
    for (int r = 0; r < 4; ++r) {
      float v = part[tm][r];
      v += __shfl_xor(v, 1);
      v += __shfl_xor(v, 2);
      v += __shfl_xor(v, 4);
      v += __shfl_xor(v, 8);
      if (ln == 0) {
        int m = wm * 64 + tm * 16 + q * 4 + r;
        atomicAdd(&scores[(size_t)b * NT + t0 + m], v);
      }
    }
  }
}

__global__ void context_kernel(const float* __restrict__ values,
                               const float* __restrict__ attn,
                               float* __restrict__ ctx) {
  int b = blockIdx.y, t0 = blockIdx.x * 128, tid = threadIdx.x;
  const float4* v4 = (const float4*)(values + (size_t)b * NT * ND);
  const float* w = attn + (size_t)b * NT + t0;
  float ax = 0.f, ay = 0.f, az = 0.f, aw = 0.f;
  for (int t = 0; t < 128; ++t) {
    float wt = w[t];
    float4 x = v4[(size_t)(t0 + t) * 256 + tid];
    ax = fmaf(wt, x.x, ax);
    ay = fmaf(wt, x.y, ay);
    az = fmaf(wt, x.z, az);
    aw = fmaf(wt, x.w, aw);
  }
  float* c = ctx + (size_t)b * ND + tid * 4;
  atomicAdd(c + 0, ax);
  atomicAdd(c + 1, ay);
  atomicAdd(c + 2, az);
  atomicAdd(c + 3, aw);
}

extern "C" void kernel_launch(void* const* d_in, const int* in_sizes, int n_in,
                              void* d_out, int out_size, void* d_ws, size_t ws_size,
                              hipStream_t stream) {
  (void)in_sizes; (void)n_in; (void)out_size;
  const float* query  = (const float*)d_in[0];
  const float* values = (const float*)d_in[1];
  const float* cov    = (const float*)d_in[2];
  const float* Wh     = (const float*)d_in[3];
  const float* bh     = (const float*)d_in[4];
  const float* Ws     = (const float*)d_in[5];
  const float* bs     = (const float*)d_in[6];
  const float* Wc     = (const float*)d_in[7];
  const float* bc     = (const float*)d_in[8];
  const float* Vw     = (const float*)d_in[9];
  // d_in[10] = Vb: softmax-invariant, unused.

  float* out = (float*)d_out;   // [0,32768)=ctx, [32768,98304)=attn, [98304,163840)=cov
  char* ws = (char*)d_ws;

  const size_t VBF = (size_t)NB * NT * ND * 2;                 // 128 MB
  const size_t O_WST = VBF;
  const size_t O_QB  = O_WST + 2u * 1024 * 1024;
  const size_t O_SC  = O_QB + 128u * 1024;
  const size_t need  = O_SC + 256u * 1024;

  if (ws_size >= need) {
    unsigned short* vbf = (unsigned short*)ws;
    unsigned short* Wst = (unsigned short*)(ws + O_WST);
    float* qb     = (float*)(ws + O_QB);
    float* scores = (float*)(ws + O_SC);

    hipMemsetAsync(scores, 0, (size_t)NB * NT * sizeof(float), stream);
    hipMemsetAsync(out, 0, (size_t)NB * ND * sizeof(float), stream);

    prep_kernel<<<34048, 256, 0, stream>>>(values, Ws, query, Wh, bh, bs, bc,
                                           vbf, Wst, qb);
    score_gemm_bf16<<<4096, 256, 0, stream>>>(vbf, Wst, qb, cov, Wc, Vw, scores);
    softmax_fused<<<NB, 256, 0, stream>>>(scores, cov, out);
    context_fused<<<dim3(16, 32), 256, 0, stream>>>(vbf, out + 32768, out);
  } else {
    unsigned short* Wst = (unsigned short*)ws;
    float* qb     = (float*)(ws + 2u * 1024 * 1024);
    float* scores = (float*)(ws + 2u * 1024 * 1024 + 128u * 1024);

    hipMemsetAsync(scores, 0, (size_t)NB * NT * sizeof(float), stream);
    hipMemsetAsync(out, 0, (size_t)NB * ND * sizeof(float), stream);

    wst_kernel<<<dim3(32, 32), 256, 0, stream>>>(Ws, Wst);
    qb_kernel2<<<dim3(8, 32), 256, 0, stream>>>(query, Wh, bh, bs, bc, qb);
    score_gemm_f32<<<dim3(8, 16, 32), 256, 0, stream>>>(values, Wst, qb, cov, Wc, Vw, scores);
    softmax_fused<<<NB, 256, 0, stream>>>(scores, cov, out);
    context_kernel<<<dim3(16, 32), 256, 0, stream>>>(values, out + 32768, out);
  }
}